// Round 7
// baseline (256.982 us; speedup 1.0000x reference)
//
#include <hip/hip_runtime.h>
#include <math.h>

#define BSZ    8192
#define DDIM   256
#define SCALE  33.33333333333333f   // 1/0.03
#define C_OFF  34.0f                // fixed LSE offset: |sim*SCALE| <= 33.34
#define SC_L2E 48.08983470f         // SCALE * log2(e)
#define C2     49.05163139f         // C_OFF * log2(e)
#define LN2    0.6931471805599453f

typedef __bf16 bf16_t;
typedef __bf16 bf16x8 __attribute__((ext_vector_type(8)));
typedef float  floatx4 __attribute__((ext_vector_type(4)));

__device__ __forceinline__ bf16x8 cvt8(const float* __restrict__ g)
{
    const float4 lo = *(const float4*)g;
    const float4 hi = *(const float4*)(g + 4);
    bf16x8 v;
    v[0] = (bf16_t)lo.x; v[1] = (bf16_t)lo.y; v[2] = (bf16_t)lo.z; v[3] = (bf16_t)lo.w;
    v[4] = (bf16_t)hi.x; v[5] = (bf16_t)hi.y; v[6] = (bf16_t)hi.z; v[7] = (bf16_t)hi.w;
    return v;
}

// ---------------------------------------------------------------- prep (zt only)
// zt -> zt_perm, chunk-ordered: 8KB g-chunk = (colblock cb, kc);
// slot P holds col cb*128+(P>>2), k = kc*32 + ((P&3)^(((P>>2)>>1)&3))*8.
// blocks<16 also zero s_row/s_col; block0 zeroes possum/cnt.
__global__ __launch_bounds__(256) void prep_kernel(
    const float* __restrict__ zt, bf16_t* __restrict__ zt_perm,
    float* __restrict__ zbase)
{
    const int bid = blockIdx.x, tid = threadIdx.x;
    const int S     = bid * 256 + tid;
    const int chunk = S >> 9, P = S & 511;
    const int col   = P >> 2, sp = P & 3;
    const int sl    = sp ^ ((col >> 1) & 3);
    const int cb    = chunk >> 3, kc = chunk & 7;
    const float* src = zt + (size_t)(cb * 128 + col) * DDIM + kc * 32 + sl * 8;
    *(bf16x8*)(zt_perm + (size_t)S * 8) = cvt8(src);

    if (bid < 16) {
        const int z = bid * 1024 + tid * 4;
        *(float4*)&zbase[z] = (float4){0.f, 0.f, 0.f, 0.f};
        if (bid == 0 && tid == 0) {
            zbase[16384] = 0.f;          // possum
            ((int*)zbase)[16385] = 0;    // cnt
        }
    }
}

// ---------------------------------------------------------------- sim + merged finalize
// Grid 64 bands x 16 strips. Wave w: rows [band*128+32w,+32), A resident (fp32
// loaded + cvt in prologue). B: 64-k chunks (16KB) via global_load_lds, 2 bufs,
// 16 barriers. Fused epilogue -> s_row/s_col/possum atomics. Last block (cnt
// handshake) computes the scalar loss.
__global__ __launch_bounds__(256, 3) void sim_fused(
    const float* __restrict__ za, const bf16_t* __restrict__ zt_perm,
    const int* __restrict__ pid,
    float* __restrict__ s_row, float* __restrict__ s_col,
    float* __restrict__ possum, int* __restrict__ cnt,
    float* __restrict__ out)
{
    __shared__ __align__(16) bf16_t Bs[2][128 * 64];   // 2 x 16 KB
    __shared__ int   pidc[512];
    __shared__ float colsum[512];
    __shared__ int   lastflag;
    __shared__ float lsw[4];
    __shared__ int   difw[4];

    const int bid   = blockIdx.x;
    const int strip = bid & 15, band = bid >> 4;
    const int row0  = band * 128, scol0 = strip * 512;
    const int tid   = threadIdx.x, lane = tid & 63, wid = tid >> 6;
    const int q     = lane >> 4, lc = lane & 15;
    const int rbase = row0 + wid * 32;
    const int qx    = (q ^ ((lc >> 1) & 3)) * 16;   // swizzled k-slot byte offset

    pidc[tid]         = pid[scol0 + tid];
    pidc[tid + 256]   = pid[scol0 + tid + 256];
    colsum[tid]       = 0.f;
    colsum[tid + 256] = 0.f;

    // A resident: af[m][kc] = A[rbase+m*16+lc][kc*32 + q*8 ..+8], cvt from fp32
    bf16x8 af[2][8];
    #pragma unroll
    for (int m = 0; m < 2; m++) {
        const float* ga = za + (size_t)(rbase + m * 16 + lc) * DDIM + q * 8;
        #pragma unroll
        for (int kc = 0; kc < 8; kc++)
            af[m][kc] = cvt8(ga + kc * 32);
    }

    int prw[2][4];
    #pragma unroll
    for (int m = 0; m < 2; m++)
        #pragma unroll
        for (int r = 0; r < 4; r++)
            prw[m][r] = pid[rbase + m * 16 + q * 4 + r];

    // staging base: strip's 32 g-chunks start at (strip*32)*8192; 64k-chunk G
    // occupies bytes [G*16384, +16384) of that — identity-mapped into Bs.
    const char* zp = (const char*)zt_perm + (size_t)(strip * 32) * 8192
                   + (wid * 64 + lane) * 16;

#define STAGE64(G, BUF)                                                          \
    do {                                                                         \
        const char* _s = zp + (size_t)(G) * 16384;                               \
        char* _d = (char*)(BUF) + wid * 1024;                                    \
        _Pragma("unroll")                                                        \
        for (int _o = 0; _o < 16384; _o += 4096)                                 \
            __builtin_amdgcn_global_load_lds(                                    \
                (const __attribute__((address_space(1))) void*)(_s + _o),        \
                (__attribute__((address_space(3))) void*)(_d + _o), 16, 0, 0);   \
    } while (0)

    STAGE64(0, Bs[0]);   // prologue

    float rowp[8] = {0.f, 0.f, 0.f, 0.f, 0.f, 0.f, 0.f, 0.f};
    float dsum = 0.f;
    const int diag_t = (row0 - scol0) >> 7;   // tile holding the diagonal if in [0,4)

    for (int t = 0; t < 4; t++) {
        floatx4 acc[2][8];
        #pragma unroll
        for (int m = 0; m < 2; m++)
            #pragma unroll
            for (int n = 0; n < 8; n++)
                acc[m][n] = (floatx4){0.f, 0.f, 0.f, 0.f};

        #pragma unroll
        for (int c2 = 0; c2 < 4; c2++) {
            __syncthreads();                  // chunk G staged (vmcnt drain @ barrier)
            const int G = t * 4 + c2;
            if (G < 15) STAGE64(G + 1, Bs[(c2 + 1) & 1]);   // fire-and-forget

            const char* B = (const char*)Bs[c2 & 1];
            #pragma unroll
            for (int h = 0; h < 2; h++) {     // 32-k halves of the 64-k chunk
                const int kc = c2 * 2 + h;
                #pragma unroll
                for (int gn = 0; gn < 2; gn++) {   // 64-col halves (reg pressure)
                    bf16x8 bfr[4];
                    #pragma unroll
                    for (int n = 0; n < 4; n++)
                        bfr[n] = *(const bf16x8*)(B + h * 8192
                                 + ((gn * 4 + n) * 16 + lc) * 64 + qx);
                    #pragma unroll
                    for (int m = 0; m < 2; m++)
                        #pragma unroll
                        for (int n = 0; n < 4; n++)
                            acc[m][gn * 4 + n] = __builtin_amdgcn_mfma_f32_16x16x32_bf16(
                                af[m][kc], bfr[n], acc[m][gn * 4 + n], 0, 0, 0);
                }
            }
        }

        // ---------- epilogue for tile t (next chunk's prefetch in flight)
        const bool isdiag = (t == diag_t);
        #pragma unroll
        for (int hn = 0; hn < 2; hn++) {      // two n-halves (reg pressure)
            int pc[4];
            float colp[4] = {0.f, 0.f, 0.f, 0.f};
            #pragma unroll
            for (int n = 0; n < 4; n++) pc[n] = pidc[t * 128 + (hn * 4 + n) * 16 + lc];

            #pragma unroll
            for (int m = 0; m < 2; m++) {
                #pragma unroll
                for (int r = 0; r < 4; r++) {
                    const int pr = prw[m][r];
                    float rsum = 0.f;
                    #pragma unroll
                    for (int n = 0; n < 4; n++) {
                        float e = __builtin_amdgcn_exp2f(
                            fmaf(acc[m][hn * 4 + n][r], SC_L2E, -C2));
                        e = (pr != pc[n]) ? e : 0.f;
                        rsum += e;
                        colp[n] += e;
                    }
                    rowp[m * 4 + r] += rsum;
                }
            }

            if (isdiag && ((wid >> 1) == hn)) {   // diagonal fixup (same-pid pair)
                // constant-index select chains only (R5 scratch-spill lesson)
                #pragma unroll
                for (int m = 0; m < 2; m++) {
                    const int ns = (wid * 2 + m) & 3;
                    #pragma unroll
                    for (int r = 0; r < 4; r++) {
                        float v = 0.f;
                        #pragma unroll
                        for (int n = 0; n < 4; n++)
                            v = (n == ns) ? acc[m][hn * 4 + n][r] : v;
                        float e = __builtin_amdgcn_exp2f(fmaf(v, SC_L2E, -C2));
                        const bool own = (lc == q * 4 + r);
                        e = own ? e : 0.f;
                        rowp[m * 4 + r] += e;
                        #pragma unroll
                        for (int n = 0; n < 4; n++)
                            colp[n] += (n == ns) ? e : 0.f;
                        dsum += own ? v * SCALE : 0.f;   // Σpos contribution
                    }
                }
            }

            #pragma unroll
            for (int n = 0; n < 4; n++) {
                colp[n] += __shfl_xor(colp[n], 16, 64);
                colp[n] += __shfl_xor(colp[n], 32, 64);
            }
            if (q == 0) {
                #pragma unroll
                for (int n = 0; n < 4; n++)
                    atomicAdd(&colsum[t * 128 + (hn * 4 + n) * 16 + lc], colp[n]);
            }
        }
    }

    // ---------- row sums
    #pragma unroll
    for (int i = 0; i < 8; i++) {
        rowp[i] += __shfl_xor(rowp[i], 1, 64);
        rowp[i] += __shfl_xor(rowp[i], 2, 64);
        rowp[i] += __shfl_xor(rowp[i], 4, 64);
        rowp[i] += __shfl_xor(rowp[i], 8, 64);
    }
    float rw = rowp[0];
    #pragma unroll
    for (int idx = 1; idx < 8; idx++)
        rw = (lc == idx) ? rowp[idx] : rw;
    if (lc < 8)
        atomicAdd(&s_row[rbase + (lc >> 2) * 16 + q * 4 + (lc & 3)], rw);

    // ---------- Σpos (diag blocks only: 256 atomics total)
    if ((unsigned)diag_t < 4u) {
        #pragma unroll
        for (int b = 1; b <= 32; b <<= 1) dsum += __shfl_xor(dsum, b, 64);
        if (lane == 0) atomicAdd(possum, dsum);
    }

    // ---------- col sums flush
    __syncthreads();
    atomicAdd(&s_col[scol0 + tid], colsum[tid]);
    atomicAdd(&s_col[scol0 + tid + 256], colsum[tid + 256]);

    // ---------- merged finalize (last block via device-scope counter)
    __threadfence();
    __syncthreads();           // all this block's atomics drained at barrier
    if (tid == 0) lastflag = (atomicAdd(cnt, 1) == (int)gridDim.x - 1);
    __syncthreads();
    if (lastflag) {
        __threadfence();
        // Σ ln over s_row||s_col (contiguous 16384 floats), coherent atomic reads
        float ls = 0.f;
        for (int j = tid; j < 16384; j += 256)
            ls += __builtin_amdgcn_logf(atomicAdd(&s_row[j], 0.f));
        ls *= LN2;
        int dif = 0;
        const int p0 = pid[0];
        for (int j = tid; j < 8192; j += 256) dif |= (pid[j] != p0);
        #pragma unroll
        for (int b = 1; b <= 32; b <<= 1) {
            ls  += __shfl_xor(ls, b, 64);
            dif |= __shfl_xor(dif, b, 64);
        }
        if (lane == 0) { lsw[wid] = ls; difw[wid] = dif; }
        __syncthreads();
        if (tid == 0) {
            float T = lsw[0] + lsw[1] + lsw[2] + lsw[3];
            const int F = difw[0] | difw[1] | difw[2] | difw[3];
            const float ps = atomicAdd(possum, 0.0f);
            T += 2.0f * (float)BSZ * C_OFF - 2.0f * ps;
            out[0] = F ? T / (2.0f * (float)BSZ) : 0.0f;
        }
    }
#undef STAGE64
}

// ---------------------------------------------------------------- launcher
extern "C" void kernel_launch(void* const* d_in, const int* in_sizes, int n_in,
                              void* d_out, int out_size, void* d_ws, size_t ws_size,
                              hipStream_t stream)
{
    const float* za  = (const float*)d_in[0];
    const float* zt  = (const float*)d_in[1];
    const int*   pid = (const int*)d_in[2];
    float* out = (float*)d_out;

    // ws: zt_perm 4MB | s_row[8192] s_col[8192] possum cnt
    bf16_t* zt_perm = (bf16_t*)d_ws;
    float*  s_row   = (float*)(zt_perm + (size_t)BSZ * DDIM);
    float*  s_col   = s_row + BSZ;
    float*  possum  = s_col + BSZ;
    int*    cnt     = (int*)(possum + 1);

    prep_kernel<<<dim3(1024), 256, 0, stream>>>(zt, zt_perm, s_row);

    sim_fused<<<dim3(1024), 256, 0, stream>>>(za, zt_perm, pid,
                                              s_row, s_col, possum, cnt, out);
}

// Round 8
// 207.136 us; speedup vs baseline: 1.2406x; 1.2406x over previous
//
#include <hip/hip_runtime.h>
#include <math.h>

#define BSZ    8192
#define DDIM   256
#define SCALE  33.33333333333333f   // 1/0.03
#define C_OFF  34.0f                // fixed LSE offset: |sim*SCALE| <= 33.34
#define SC_L2E 48.08983470f         // SCALE * log2(e)
#define C2     49.05163139f         // C_OFF * log2(e)
#define LN2    0.6931471805599453f

typedef __bf16 bf16_t;
typedef __bf16 bf16x8 __attribute__((ext_vector_type(8)));
typedef float  floatx4 __attribute__((ext_vector_type(4)));

__device__ __forceinline__ bf16x8 cvt8(const float* __restrict__ g)
{
    const float4 lo = *(const float4*)g;
    const float4 hi = *(const float4*)(g + 4);
    bf16x8 v;
    v[0] = (bf16_t)lo.x; v[1] = (bf16_t)lo.y; v[2] = (bf16_t)lo.z; v[3] = (bf16_t)lo.w;
    v[4] = (bf16_t)hi.x; v[5] = (bf16_t)hi.y; v[6] = (bf16_t)hi.z; v[7] = (bf16_t)hi.w;
    return v;
}

// ---------------------------------------------------------------- prep (zt only)
// zt -> zt_perm, chunk-ordered: 8KB chunk = (colblock cb, kc);
// slot P holds col cb*128+(P>>2), k = kc*32 + ((P&3)^(((P>>2)>>1)&3))*8.
// blocks<16 zero s_row/s_col; block0 zeroes possum/cnt.  (verified R7)
__global__ __launch_bounds__(256) void prep_kernel(
    const float* __restrict__ zt, bf16_t* __restrict__ zt_perm,
    float* __restrict__ zbase)
{
    const int bid = blockIdx.x, tid = threadIdx.x;
    const int S     = bid * 256 + tid;
    const int chunk = S >> 9, P = S & 511;
    const int col   = P >> 2, sp = P & 3;
    const int sl    = sp ^ ((col >> 1) & 3);
    const int cb    = chunk >> 3, kc = chunk & 7;
    const float* src = zt + (size_t)(cb * 128 + col) * DDIM + kc * 32 + sl * 8;
    *(bf16x8*)(zt_perm + (size_t)S * 8) = cvt8(src);

    if (bid < 16) {
        const int z = bid * 1024 + tid * 4;
        *(float4*)&zbase[z] = (float4){0.f, 0.f, 0.f, 0.f};
        if (bid == 0 && tid == 0) {
            zbase[16384] = 0.f;          // possum
            ((int*)zbase)[16385] = 0;    // cnt
        }
    }
}

// ---------------------------------------------------------------- sim + merged finalize
// R6-proven core (launch_bounds(256,2), VGPR~112 — (256,3) spills, R7: 51MB
// scratch writes). 128-k chunks: 2 x 32KB LDS buffers, 8 barriers/block
// (R6 had 32). pid read from global; col partials atomicAdd direct to s_col.
__global__ __launch_bounds__(256, 2) void sim_fused(
    const float* __restrict__ za, const bf16_t* __restrict__ zt_perm,
    const int* __restrict__ pid,
    float* __restrict__ s_row, float* __restrict__ s_col,
    float* __restrict__ possum, int* __restrict__ cnt,
    float* __restrict__ out)
{
    __shared__ __align__(16) char smem[65536];            // 2 x 32KB B buffers
    bf16_t* Bs0 = (bf16_t*)smem;
    bf16_t* Bs1 = (bf16_t*)(smem + 32768);

    const int bid   = blockIdx.x;
    const int strip = bid & 15, band = bid >> 4;
    const int row0  = band * 128, scol0 = strip * 512;
    const int tid   = threadIdx.x, lane = tid & 63, wid = tid >> 6;
    const int q     = lane >> 4, lc = lane & 15;
    const int rbase = row0 + wid * 32;
    const int qx    = (q ^ ((lc >> 1) & 3)) * 16;         // swizzled k-slot byte offset

    // A resident: af[m][kc] = A[rbase+m*16+lc][kc*32 + q*8 ..+8], cvt from fp32
    bf16x8 af[2][8];
    #pragma unroll
    for (int m = 0; m < 2; m++) {
        const float* ga = za + (size_t)(rbase + m * 16 + lc) * DDIM + q * 8;
        #pragma unroll
        for (int kc = 0; kc < 8; kc++)
            af[m][kc] = cvt8(ga + kc * 32);
    }

    int prw[2][4];
    #pragma unroll
    for (int m = 0; m < 2; m++)
        #pragma unroll
        for (int r = 0; r < 4; r++)
            prw[m][r] = pid[rbase + m * 16 + q * 4 + r];

    // staging: strip's data = zt_perm bytes [strip*256KB, +256KB); 32KB half H
    // (H=0..7) at +H*32768, identity-mapped into a buffer. src carries lane*16;
    // LDS dst is wave-uniform (HW scatters lane*16).
    const char* zsrc = (const char*)zt_perm + (size_t)strip * 262144
                     + wid * 1024 + lane * 16;

#define STAGE32(H, BUF)                                                          \
    do {                                                                         \
        const char* _s = zsrc + (size_t)(H) * 32768;                             \
        char* _d = (char*)(BUF) + wid * 1024;                                    \
        _Pragma("unroll")                                                        \
        for (int _r = 0; _r < 8; _r++)                                           \
            __builtin_amdgcn_global_load_lds(                                    \
                (const __attribute__((address_space(1))) void*)(_s + _r * 4096), \
                (__attribute__((address_space(3))) void*)(_d + _r * 4096),       \
                16, 0, 0);                                                       \
    } while (0)

    STAGE32(0, Bs0);   // prologue

    float rowp[8] = {0.f, 0.f, 0.f, 0.f, 0.f, 0.f, 0.f, 0.f};
    float dsum = 0.f;
    const int diag_t = (row0 - scol0) >> 7;   // tile holding the diagonal if in [0,4)

    for (int t = 0; t < 4; t++) {
        floatx4 acc[2][8];
        #pragma unroll
        for (int m = 0; m < 2; m++)
            #pragma unroll
            for (int n = 0; n < 8; n++)
                acc[m][n] = (floatx4){0.f, 0.f, 0.f, 0.f};

        #pragma unroll
        for (int h2 = 0; h2 < 2; h2++) {      // 128-k halves of the tile's K=256
            __syncthreads();                  // half H staged (vmcnt drain @ barrier)
            const int H = t * 2 + h2;
            if (H < 7) STAGE32(H + 1, (H & 1) ? Bs0 : Bs1);   // fire-and-forget

            const char* B = (const char*)((H & 1) ? Bs1 : Bs0);
            #pragma unroll
            for (int kcl = 0; kcl < 4; kcl++) {
                const int kc = h2 * 4 + kcl;
                bf16x8 bfr[8];
                #pragma unroll
                for (int n = 0; n < 8; n++)
                    bfr[n] = *(const bf16x8*)(B + kcl * 8192 + (n * 16 + lc) * 64 + qx);
                #pragma unroll
                for (int m = 0; m < 2; m++)
                    #pragma unroll
                    for (int n = 0; n < 8; n++)
                        acc[m][n] = __builtin_amdgcn_mfma_f32_16x16x32_bf16(
                            af[m][kc], bfr[n], acc[m][n], 0, 0, 0);
            }
        }

        // ---------- epilogue for tile t (next half's prefetch in flight)
        int pc[8];
        #pragma unroll
        for (int n = 0; n < 8; n++) pc[n] = pid[scol0 + t * 128 + n * 16 + lc];

        float colp[8] = {0.f, 0.f, 0.f, 0.f, 0.f, 0.f, 0.f, 0.f};
        #pragma unroll
        for (int m = 0; m < 2; m++) {
            #pragma unroll
            for (int r = 0; r < 4; r++) {
                const int pr = prw[m][r];
                float rsum = 0.f;
                #pragma unroll
                for (int n = 0; n < 8; n++) {
                    float e = __builtin_amdgcn_exp2f(fmaf(acc[m][n][r], SC_L2E, -C2));
                    e = (pr != pc[n]) ? e : 0.f;
                    rsum += e;
                    colp[n] += e;
                }
                rowp[m * 4 + r] += rsum;
            }
        }

        if (t == diag_t) {   // diagonal fixup — constant-index select chains only
            #pragma unroll
            for (int m = 0; m < 2; m++) {
                const int nstar = wid * 2 + m;
                #pragma unroll
                for (int r = 0; r < 4; r++) {
                    float v = 0.f;
                    #pragma unroll
                    for (int n = 0; n < 8; n++)
                        v = (n == nstar) ? acc[m][n][r] : v;
                    float e = __builtin_amdgcn_exp2f(fmaf(v, SC_L2E, -C2));
                    const bool own = (lc == q * 4 + r);
                    e = own ? e : 0.f;
                    rowp[m * 4 + r] += e;
                    #pragma unroll
                    for (int n = 0; n < 8; n++)
                        colp[n] += (n == nstar) ? e : 0.f;
                    dsum += own ? v * SCALE : 0.f;
                }
            }
        }

        // col partials: reduce across quads, q==0 lanes atomicAdd direct to global
        #pragma unroll
        for (int n = 0; n < 8; n++) {
            colp[n] += __shfl_xor(colp[n], 16, 64);
            colp[n] += __shfl_xor(colp[n], 32, 64);
        }
        if (q == 0) {
            #pragma unroll
            for (int n = 0; n < 8; n++)
                atomicAdd(&s_col[scol0 + t * 128 + n * 16 + lc], colp[n]);
        }
    }

    // ---------- row sums
    #pragma unroll
    for (int i = 0; i < 8; i++) {
        rowp[i] += __shfl_xor(rowp[i], 1, 64);
        rowp[i] += __shfl_xor(rowp[i], 2, 64);
        rowp[i] += __shfl_xor(rowp[i], 4, 64);
        rowp[i] += __shfl_xor(rowp[i], 8, 64);
    }
    float rw = rowp[0];
    #pragma unroll
    for (int idx = 1; idx < 8; idx++)
        rw = (lc == idx) ? rowp[idx] : rw;
    if (lc < 8)
        atomicAdd(&s_row[rbase + (lc >> 2) * 16 + q * 4 + (lc & 3)], rw);

    // ---------- Σpos (diag blocks only)
    if ((unsigned)diag_t < 4u) {
        #pragma unroll
        for (int b = 1; b <= 32; b <<= 1) dsum += __shfl_xor(dsum, b, 64);
        if (lane == 0) atomicAdd(possum, dsum);
    }

    // ---------- merged finalize (last block); scratch reuses dead B LDS
    float* lsw      = (float*)smem;          // [4]
    int*   difw     = (int*)(smem + 16);     // [4]
    int*   lastflag = (int*)(smem + 32);

    __threadfence();
    __syncthreads();           // all waves' atomics fenced; Bs dead
    if (tid == 0) *lastflag = (atomicAdd(cnt, 1) == (int)gridDim.x - 1);
    __syncthreads();
    if (*lastflag) {
        __threadfence();
        float ls = 0.f;        // Σ ln over s_row||s_col (contiguous 16384 floats)
        for (int j = tid; j < 16384; j += 256)
            ls += __builtin_amdgcn_logf(atomicAdd(&s_row[j], 0.f));
        ls *= LN2;
        int dif = 0;
        const int p0 = pid[0];
        for (int j = tid; j < 8192; j += 256) dif |= (pid[j] != p0);
        #pragma unroll
        for (int b = 1; b <= 32; b <<= 1) {
            ls  += __shfl_xor(ls, b, 64);
            dif |= __shfl_xor(dif, b, 64);
        }
        if (lane == 0) { lsw[wid] = ls; difw[wid] = dif; }
        __syncthreads();
        if (tid == 0) {
            float T = lsw[0] + lsw[1] + lsw[2] + lsw[3];
            const int F = difw[0] | difw[1] | difw[2] | difw[3];
            const float ps = atomicAdd(possum, 0.0f);
            T += 2.0f * (float)BSZ * C_OFF - 2.0f * ps;
            out[0] = F ? T / (2.0f * (float)BSZ) : 0.0f;
        }
    }
#undef STAGE32
}

// ---------------------------------------------------------------- launcher
extern "C" void kernel_launch(void* const* d_in, const int* in_sizes, int n_in,
                              void* d_out, int out_size, void* d_ws, size_t ws_size,
                              hipStream_t stream)
{
    const float* za  = (const float*)d_in[0];
    const float* zt  = (const float*)d_in[1];
    const int*   pid = (const int*)d_in[2];
    float* out = (float*)d_out;

    // ws: zt_perm 4MB | s_row[8192] s_col[8192] possum cnt
    bf16_t* zt_perm = (bf16_t*)d_ws;
    float*  s_row   = (float*)(zt_perm + (size_t)BSZ * DDIM);
    float*  s_col   = s_row + BSZ;
    float*  possum  = s_col + BSZ;
    int*    cnt     = (int*)(possum + 1);

    prep_kernel<<<dim3(1024), 256, 0, stream>>>(zt, zt_perm, s_row);

    sim_fused<<<dim3(1024), 256, 0, stream>>>(za, zt_perm, pid,
                                              s_row, s_col, possum, cnt, out);
}